// Round 1
// baseline (494.608 us; speedup 1.0000x reference)
//
#include <hip/hip_runtime.h>
#include <hip/hip_cooperative_groups.h>

namespace cg = cooperative_groups;

#define BN    64
#define KCLS  3
#define PPIX  147456
#define NB1   4096
#define NB3   128
#define CAP   8192

// fused (cooperative) geometry
#define NBLK      1024           // 64 rows x 16 chunks = 4 blocks/CU on 256 CUs
#define CPR       16             // chunks per row
#define F4PB      2304           // float4 groups per block (9216 px)
#define VPT       9              // float4 groups per thread
#define STAGE_CAP 2048           // LDS staging cap per block (overflow -> direct global)

// fallback (old) geometry
#define BPR    36
#define F4_BLK 1024
#define PX_BLK 4096

// ---------------- workspace layout (bytes) ----------------
static const size_t OFF_NLL  = 0;                                   // 37,748,736 (fallback only)
static const size_t OFF_CAND = OFF_NLL + (size_t)BN * PPIX * 4;     // 2 MB
static const size_t OFF_C1   = OFF_CAND + (size_t)BN * CAP * 4;     // 1 MB (zeroed) - ghist
static const size_t OFF_CCNT = OFF_C1 + (size_t)BN * NB1 * 4;       // 256 B (zeroed)
static const size_t OFF_SS   = OFF_CCNT + 256;                      // 512 B (zeroed)
static const size_t OFF_ACC  = OFF_SS + 512;                        // 8 B   (zeroed)
static const size_t OFF_DONE = OFF_ACC + 8;                         // 8 B   (zeroed)
static const size_t ZERO_END = OFF_DONE + 8;
static const size_t OFF_B1   = ZERO_END;                            // fallback st_b1
static const size_t OFF_R1   = ZERO_END + 256;                      // fallback st_r1

__device__ __forceinline__ unsigned topk_count(const int* sp_ptr) {
    double sp = (double)sp_ptr[0];
    if (sp > 1.0) sp = 1.0;
    return (unsigned)(sp * 0.15 * (double)PPIX + (1.0 - sp) * (double)PPIX);
}

__device__ __forceinline__ float sel_nll(int t, float a, float b, float c) {
    float lp = (t == 0) ? a : ((t == 1) ? b : ((t == 2) ? c : 0.0f));
    return fmaxf(-lp, 0.0f);   // nll >= 0; kill -0.0
}

// device-scope (cross-XCD coherent) loads — workspace is reused across graph
// replays, so plain loads can hit stale per-XCD L1/L2 lines.
__device__ __forceinline__ unsigned ld_au32(const unsigned* p) {
    return __hip_atomic_load(p, __ATOMIC_RELAXED, __HIP_MEMORY_SCOPE_AGENT);
}
__device__ __forceinline__ int ld_ai32(const int* p) {
    return __hip_atomic_load(p, __ATOMIC_RELAXED, __HIP_MEMORY_SCOPE_AGENT);
}
__device__ __forceinline__ float ld_af32(const float* p) {
    return __hip_atomic_load(p, __ATOMIC_RELAXED, __HIP_MEMORY_SCOPE_AGENT);
}
__device__ __forceinline__ double ld_af64(const double* p) {
    return __hip_atomic_load(p, __ATOMIC_RELAXED, __HIP_MEMORY_SCOPE_AGENT);
}

// ======================= fused cooperative kernel ===========================
struct SMemA { unsigned lc[NB1]; };                                          // 16 KB
struct SMemC { unsigned csum[256]; float stage[STAGE_CAP]; double dred[256]; }; // 11.25 KB
struct SMemD { unsigned lc[NB1]; float ls[NB1]; unsigned csum[256]; double ssum[256]; }; // 35 KB
union  SMemU { SMemA a; SMemC c; SMemD d; };

__global__ __launch_bounds__(256, 4) void k_fused(
    const float* __restrict__ in, const int* __restrict__ tgt,
    const int* __restrict__ sp, unsigned* __restrict__ ghist,
    float* __restrict__ cand, int* __restrict__ ccnt,
    double* __restrict__ st_S, double* __restrict__ accum,
    unsigned* __restrict__ done, float* __restrict__ out)
{
    __shared__ SMemU sm;
    __shared__ int s_b1, s_r1, s_lcnt, s_gbase;
    __shared__ int s_b2, s_r2;
    __shared__ double s_S2;
    cg::grid_group grid = cg::this_grid();

    const int tid   = threadIdx.x;
    const int bid   = blockIdx.x;
    const int row   = bid >> 4;
    const int chunk = bid & (CPR - 1);

    // ---------------- phase A: NLL (kept in registers) + histogram ----------
    for (int i = tid; i < NB1; i += 256) sm.a.lc[i] = 0u;
    __syncthreads();

    const float4* p0 = (const float4*)(in + (size_t)row * KCLS * PPIX);
    const float4* p1 = p0 + PPIX / 4;
    const float4* p2 = p1 + PPIX / 4;
    const int4*   t4 = (const int4*)(tgt + (size_t)row * PPIX);
    const int base = chunk * F4PB;

    float4 v[VPT];
    #pragma unroll
    for (int j = 0; j < VPT; ++j) {
        const int idx = base + j * 256 + tid;
        const int4   t = t4[idx];
        const float4 a = p0[idx];
        const float4 b = p1[idx];
        const float4 c = p2[idx];
        float4 w;
        w.x = sel_nll(t.x, a.x, b.x, c.x);
        w.y = sel_nll(t.y, a.y, b.y, c.y);
        w.z = sel_nll(t.z, a.z, b.z, c.z);
        w.w = sel_nll(t.w, a.w, b.w, c.w);
        v[j] = w;
        atomicAdd(&sm.a.lc[__float_as_uint(w.x) >> 19], 1u);
        atomicAdd(&sm.a.lc[__float_as_uint(w.y) >> 19], 1u);
        atomicAdd(&sm.a.lc[__float_as_uint(w.z) >> 19], 1u);
        atomicAdd(&sm.a.lc[__float_as_uint(w.w) >> 19], 1u);
    }
    __syncthreads();
    {
        unsigned* gh = ghist + (size_t)row * NB1;
        for (int i = tid; i < NB1; i += 256) {
            const unsigned cc = sm.a.lc[i];
            if (cc) atomicAdd(&gh[i], cc);   // device-scope atomic: coherent
        }
    }
    grid.sync();

    // ---------------- phase C: per-row scan (redundant per block) -----------
    const unsigned* ghr = ghist + (size_t)row * NB1;
    unsigned cl[16]; unsigned cacc = 0u;
    const int cbase = tid * 16;
    #pragma unroll
    for (int i = 0; i < 16; ++i) {
        cl[i] = ld_au32(&ghr[NB1 - 1 - (cbase + i)]);
        cacc += cl[i];
    }
    sm.c.csum[tid] = cacc;
    __syncthreads();
    for (int off = 1; off < 256; off <<= 1) {
        unsigned t2 = (tid >= off) ? sm.c.csum[tid - off] : 0u;
        __syncthreads();
        sm.c.csum[tid] += t2;
        __syncthreads();
    }
    const unsigned k = topk_count(sp);
    {
        unsigned cum = tid ? sm.c.csum[tid - 1] : 0u;
        #pragma unroll
        for (int i = 0; i < 16; ++i) {
            const unsigned cb = cl[i];
            if (cum < k && cum + cb >= k) {      // exactly one (thread,i) hits
                s_b1 = NB1 - 1 - (cbase + i);
                s_r1 = (int)(k - cum);
            }
            cum += cb;
        }
    }
    if (tid == 0) s_lcnt = 0;
    __syncthreads();

    // ---------------- S_above (f64) + compact bin-b1 candidates (from regs) -
    const unsigned b1 = (unsigned)s_b1;
    const unsigned lo = b1 << 19;
    const unsigned hi = (b1 + 1u) << 19;   // b1==4095 -> 0x80000000 > all v>=0
    int*   ccr = &ccnt[row];
    float* cr  = cand + (size_t)row * CAP;

    double acc = 0.0;
    #pragma unroll
    for (int j = 0; j < VPT; ++j) {
        const float vv[4] = {v[j].x, v[j].y, v[j].z, v[j].w};
        #pragma unroll
        for (int q = 0; q < 4; ++q) {
            const unsigned u = __float_as_uint(vv[q]);
            if (u >= hi) {
                acc += (double)vv[q];
            } else if (u >= lo) {
                const int s = atomicAdd(&s_lcnt, 1);
                if (s < STAGE_CAP) {
                    sm.c.stage[s] = vv[q];
                } else {                       // overflow slow path (rare)
                    const int gp = atomicAdd(ccr, 1);
                    if (gp < CAP) cr[gp] = vv[q];
                }
            }
        }
    }
    sm.c.dred[tid] = acc;
    __syncthreads();
    for (int s = 128; s > 0; s >>= 1) {
        if (tid < s) sm.c.dred[tid] += sm.c.dred[tid + s];
        __syncthreads();
    }
    if (tid == 0) {
        atomicAdd(&st_S[row], sm.c.dred[0]);       // native f64 global atomic
        int nst = s_lcnt; if (nst > STAGE_CAP) nst = STAGE_CAP;
        s_gbase = atomicAdd(ccr, nst);
    }
    __syncthreads();
    {
        int nst = s_lcnt; if (nst > STAGE_CAP) nst = STAGE_CAP;
        const int gb = s_gbase;
        for (int i = tid; i < nst; i += 256) {
            const int pos = gb + i;
            if (pos < CAP) cr[pos] = sm.c.stage[i];
        }
    }
    __threadfence();           // flush plain cand stores device-wide
    grid.sync();

    // ---------------- phase D: per-row resolve (chunk-0 blocks only) --------
    if (chunk != 0) return;

    int n = ld_ai32(ccr); if (n > CAP) n = CAP;

    // level 2: hist over bits[18:7]
    for (int i = tid; i < NB1; i += 256) { sm.d.lc[i] = 0u; sm.d.ls[i] = 0.0f; }
    __syncthreads();
    for (int i = tid; i < n; i += 256) {
        const float vv2 = ld_af32(&cr[i]);
        const unsigned key = (__float_as_uint(vv2) >> 7) & 0xFFFu;
        atomicAdd(&sm.d.lc[key], 1u);
        atomicAdd(&sm.d.ls[key], vv2);
    }
    __syncthreads();

    {
        unsigned cl2[16]; float slv[16];
        unsigned cacc2 = 0; double sacc = 0.0;
        #pragma unroll
        for (int i = 0; i < 16; ++i) {
            const int bin = NB1 - 1 - (cbase + i);
            cl2[i] = sm.d.lc[bin];
            slv[i] = sm.d.ls[bin];
            cacc2 += cl2[i];
            sacc  += (double)slv[i];
        }
        sm.d.csum[tid] = cacc2; sm.d.ssum[tid] = sacc;
        __syncthreads();
        for (int off = 1; off < 256; off <<= 1) {
            unsigned cv2 = 0; double sv = 0.0;
            if (tid >= off) { cv2 = sm.d.csum[tid - off]; sv = sm.d.ssum[tid - off]; }
            __syncthreads();
            sm.d.csum[tid] += cv2; sm.d.ssum[tid] += sv;
            __syncthreads();
        }
        const unsigned k2 = (unsigned)s_r1;
        unsigned cum = tid ? sm.d.csum[tid - 1] : 0u;
        double   sS  = tid ? sm.d.ssum[tid - 1] : 0.0;
        #pragma unroll
        for (int i = 0; i < 16; ++i) {
            const unsigned cb = cl2[i];
            if (cum < k2 && cum + cb >= k2) {
                s_b2 = NB1 - 1 - (cbase + i);
                s_r2 = (int)(k2 - cum);
                s_S2 = sS;
            }
            cum += cb;
            sS  += (double)slv[i];
        }
    }
    __syncthreads();

    // level 3: 128-bin hist over bits[6:0], prefix = bits[30:7]
    const unsigned pref = ((unsigned)s_b1 << 12) | (unsigned)s_b2;
    if (tid < NB3) { sm.d.lc[tid] = 0u; sm.d.ls[tid] = 0.0f; }
    __syncthreads();
    for (int i = tid; i < n; i += 256) {
        const float vv2 = ld_af32(&cr[i]);
        const unsigned bits = __float_as_uint(vv2);
        if ((bits >> 7) == pref) {
            atomicAdd(&sm.d.lc[bits & 0x7Fu], 1u);
            atomicAdd(&sm.d.ls[bits & 0x7Fu], vv2);
        }
    }
    __syncthreads();
    if (tid == 0) {
        const unsigned k3 = (unsigned)s_r2;
        unsigned cum3 = 0, r3 = 0; int b3 = 0; double S3 = 0.0;
        for (int bin = NB3 - 1; bin >= 0; --bin) {
            const unsigned cb = sm.d.lc[bin];
            if (cum3 < k3 && cum3 + cb >= k3) { b3 = bin; r3 = k3 - cum3; break; }
            cum3 += cb;
            S3   += (double)sm.d.ls[bin];
        }
        const float tval = __uint_as_float((pref << 7) | (unsigned)b3);
        const double total = ld_af64(&st_S[row]) + s_S2 + S3 + (double)r3 * (double)tval;
        atomicAdd(accum, total);
        __threadfence();
        const unsigned ticket = atomicAdd(done, 1u);   // last row writes mean
        if (ticket == BN - 1) {
            __threadfence();
            const double a2 = ld_af64(accum);
            out[0] = (float)(a2 / ((double)BN * (double)topk_count(sp)));
        }
    }
}

// ======================= fallback path (previous verified kernels) ==========
__global__ __launch_bounds__(256) void k_hist1(
    const float* __restrict__ in, const int* __restrict__ tgt,
    float* __restrict__ nll, unsigned* __restrict__ cnt1)
{
    __shared__ unsigned lc[NB1];
    const int tid = threadIdx.x;
    for (int i = tid; i < NB1; i += 256) lc[i] = 0u;
    __syncthreads();

    const int row   = blockIdx.x / BPR;
    const int chunk = blockIdx.x % BPR;
    const float4* p0 = (const float4*)(in + (size_t)row * KCLS * PPIX);
    const float4* p1 = p0 + PPIX / 4;
    const float4* p2 = p1 + PPIX / 4;
    const int4*   t4 = (const int4*)(tgt + (size_t)row * PPIX);
    float4*       n4 = (float4*)(nll + (size_t)row * PPIX);
    const int base = chunk * F4_BLK;

    #pragma unroll
    for (int j = 0; j < 4; ++j) {
        const int idx = base + j * 256 + tid;
        const int4   t = t4[idx];
        const float4 a = p0[idx];
        const float4 b = p1[idx];
        const float4 c = p2[idx];
        float4 v;
        v.x = sel_nll(t.x, a.x, b.x, c.x);
        v.y = sel_nll(t.y, a.y, b.y, c.y);
        v.z = sel_nll(t.z, a.z, b.z, c.z);
        v.w = sel_nll(t.w, a.w, b.w, c.w);
        n4[idx] = v;
        atomicAdd(&lc[__float_as_uint(v.x) >> 19], 1u);
        atomicAdd(&lc[__float_as_uint(v.y) >> 19], 1u);
        atomicAdd(&lc[__float_as_uint(v.z) >> 19], 1u);
        atomicAdd(&lc[__float_as_uint(v.w) >> 19], 1u);
    }
    __syncthreads();

    unsigned* gc = cnt1 + (size_t)row * NB1;
    for (int i = tid; i < NB1; i += 256) {
        const unsigned cc = lc[i];
        if (cc) atomicAdd(&gc[i], cc);
    }
}

__global__ __launch_bounds__(256) void k_scan(
    const unsigned* __restrict__ cnt, const int* __restrict__ sp_ptr,
    int* __restrict__ st_b, int* __restrict__ st_r)
{
    const int row = blockIdx.x, tid = threadIdx.x;
    __shared__ unsigned csum[256];
    const unsigned* c = cnt + (size_t)row * NB1;

    unsigned cl[16]; unsigned cacc = 0;
    const int base = tid * 16;
    #pragma unroll
    for (int i = 0; i < 16; ++i) {
        cl[i] = c[NB1 - 1 - (base + i)];
        cacc += cl[i];
    }
    csum[tid] = cacc;
    __syncthreads();
    for (int off = 1; off < 256; off <<= 1) {
        unsigned t2 = (tid >= off) ? csum[tid - off] : 0u;
        __syncthreads();
        csum[tid] += t2;
        __syncthreads();
    }
    const unsigned k = topk_count(sp_ptr);
    unsigned cum = tid ? csum[tid - 1] : 0u;
    #pragma unroll
    for (int i = 0; i < 16; ++i) {
        const unsigned cb = cl[i];
        if (cum < k && cum + cb >= k) {
            st_b[row] = NB1 - 1 - (base + i);
            st_r[row] = (int)(k - cum);
        }
        cum += cb;
    }
}

__global__ __launch_bounds__(256) void k_compact(
    const float* __restrict__ nll, const int* __restrict__ st_b1,
    float* __restrict__ cand, int* __restrict__ ccnt, double* __restrict__ st_S)
{
    __shared__ float  stage[PX_BLK];
    __shared__ double dred[256];
    __shared__ int lcnt, gbase;
    const int tid = threadIdx.x;
    if (tid == 0) lcnt = 0;
    __syncthreads();

    const int row   = blockIdx.x / BPR;
    const int chunk = blockIdx.x % BPR;
    const unsigned b1 = (unsigned)st_b1[row];
    const unsigned lo = b1 << 19;
    const unsigned hi = (b1 + 1u) << 19;
    const float4* n4 = (const float4*)(nll + (size_t)row * PPIX);
    const int base = chunk * F4_BLK;

    double acc = 0.0;
    #pragma unroll
    for (int j = 0; j < 4; ++j) {
        const float4 f = n4[base + j * 256 + tid];
        const float vv[4] = {f.x, f.y, f.z, f.w};
        #pragma unroll
        for (int q = 0; q < 4; ++q) {
            const unsigned u = __float_as_uint(vv[q]);
            if (u >= hi) {
                acc += (double)vv[q];
            } else if (u >= lo) {
                const int s = atomicAdd(&lcnt, 1);
                stage[s] = vv[q];
            }
        }
    }
    dred[tid] = acc;
    __syncthreads();
    for (int s = 128; s > 0; s >>= 1) {
        if (tid < s) dred[tid] += dred[tid + s];
        __syncthreads();
    }
    if (tid == 0) {
        atomicAdd(&st_S[row], dred[0]);
        gbase = atomicAdd(&ccnt[row], lcnt);
    }
    __syncthreads();
    const int n = lcnt, gb = gbase;
    float* cr = cand + (size_t)row * CAP;
    for (int i = tid; i < n; i += 256) {
        const int pos = gb + i;
        if (pos < CAP) cr[pos] = stage[i];
    }
}

__global__ __launch_bounds__(256) void k_resolve(
    const float* __restrict__ cand, const int* __restrict__ ccnt,
    const int* __restrict__ st_b1, const int* __restrict__ st_r1,
    const double* __restrict__ st_S, double* __restrict__ accum)
{
    __shared__ unsigned lc[NB1];
    __shared__ float    ls[NB1];
    __shared__ unsigned csum[256];
    __shared__ double   ssum[256];
    __shared__ int sb2, sr2;
    __shared__ double sS2;

    const int row = blockIdx.x, tid = threadIdx.x;
    int n = ccnt[row]; if (n > CAP) n = CAP;
    const float* cv = cand + (size_t)row * CAP;

    for (int i = tid; i < NB1; i += 256) { lc[i] = 0u; ls[i] = 0.0f; }
    __syncthreads();
    for (int i = tid; i < n; i += 256) {
        const float v = cv[i];
        const unsigned key = (__float_as_uint(v) >> 7) & 0xFFFu;
        atomicAdd(&lc[key], 1u);
        atomicAdd(&ls[key], v);
    }
    __syncthreads();

    unsigned cl[16]; float slv[16];
    unsigned cacc = 0; double sacc = 0.0;
    const int base = tid * 16;
    #pragma unroll
    for (int i = 0; i < 16; ++i) {
        const int bin = NB1 - 1 - (base + i);
        cl[i]  = lc[bin];
        slv[i] = ls[bin];
        cacc += cl[i];
        sacc += (double)slv[i];
    }
    csum[tid] = cacc; ssum[tid] = sacc;
    __syncthreads();
    for (int off = 1; off < 256; off <<= 1) {
        unsigned cv2 = 0; double sv = 0.0;
        if (tid >= off) { cv2 = csum[tid - off]; sv = ssum[tid - off]; }
        __syncthreads();
        csum[tid] += cv2; ssum[tid] += sv;
        __syncthreads();
    }
    const unsigned k = (unsigned)st_r1[row];
    unsigned cum = tid ? csum[tid - 1] : 0u;
    double   sS  = tid ? ssum[tid - 1] : 0.0;
    #pragma unroll
    for (int i = 0; i < 16; ++i) {
        const unsigned cb = cl[i];
        if (cum < k && cum + cb >= k) {
            sb2 = NB1 - 1 - (base + i);
            sr2 = (int)(k - cum);
            sS2 = sS;
        }
        cum += cb;
        sS  += (double)slv[i];
    }
    __syncthreads();

    const unsigned pref = ((unsigned)st_b1[row] << 12) | (unsigned)sb2;
    if (tid < NB3) { lc[tid] = 0u; ls[tid] = 0.0f; }
    __syncthreads();
    for (int i = tid; i < n; i += 256) {
        const float v = cv[i];
        const unsigned bits = __float_as_uint(v);
        if ((bits >> 7) == pref) {
            atomicAdd(&lc[bits & 0x7Fu], 1u);
            atomicAdd(&ls[bits & 0x7Fu], v);
        }
    }
    __syncthreads();
    if (tid == 0) {
        const unsigned k3 = (unsigned)sr2;
        unsigned cum3 = 0, r3 = 0; int b3 = 0; double S3 = 0.0;
        for (int bin = NB3 - 1; bin >= 0; --bin) {
            const unsigned cb = lc[bin];
            if (cum3 < k3 && cum3 + cb >= k3) { b3 = bin; r3 = k3 - cum3; break; }
            cum3 += cb;
            S3   += (double)ls[bin];
        }
        const float tval = __uint_as_float((pref << 7) | (unsigned)b3);
        const double total = st_S[row] + sS2 + S3 + (double)r3 * (double)tval;
        atomicAdd(accum, total);
    }
}

__global__ void k_out(const double* __restrict__ accum, const int* __restrict__ sp_ptr,
                      float* __restrict__ out)
{
    if (threadIdx.x == 0 && blockIdx.x == 0) {
        const unsigned k = topk_count(sp_ptr);
        out[0] = (float)(accum[0] / ((double)BN * (double)k));
    }
}

// ======================= launch =============================================
extern "C" void kernel_launch(void* const* d_in, const int* in_sizes, int n_in,
                              void* d_out, int out_size, void* d_ws, size_t ws_size,
                              hipStream_t stream)
{
    (void)in_sizes; (void)n_in; (void)out_size; (void)ws_size;
    const float* in  = (const float*)d_in[0];
    const int*   tgt = (const int*)d_in[1];
    const int*   sp  = (const int*)d_in[2];

    char* ws = (char*)d_ws;
    float*    nll   = (float*)(ws + OFF_NLL);
    float*    cand  = (float*)(ws + OFF_CAND);
    unsigned* ghist = (unsigned*)(ws + OFF_C1);
    int*      ccnt  = (int*)(ws + OFF_CCNT);
    double*   st_S  = (double*)(ws + OFF_SS);
    double*   accum = (double*)(ws + OFF_ACC);
    unsigned* done  = (unsigned*)(ws + OFF_DONE);
    int*      st_b1 = (int*)(ws + OFF_B1);
    int*      st_r1 = (int*)(ws + OFF_R1);
    float*    outp  = (float*)d_out;

    // zero: ghist + ccnt + st_S + accum + done
    hipMemsetAsync(ws + OFF_C1, 0, ZERO_END - OFF_C1, stream);

    void* kargs[] = {
        (void*)&in, (void*)&tgt, (void*)&sp, (void*)&ghist, (void*)&cand,
        (void*)&ccnt, (void*)&st_S, (void*)&accum, (void*)&done, (void*)&outp
    };
    hipError_t err = hipLaunchCooperativeKernel(
        (const void*)k_fused, dim3(NBLK), dim3(256), kargs, 0, stream);

    if (err != hipSuccess) {
        // fallback: previous verified 5-kernel pipeline
        const int blocks = BN * BPR;   // 2304
        k_hist1  <<<blocks, 256, 0, stream>>>(in, tgt, nll, ghist);
        k_scan   <<<BN, 256, 0, stream>>>(ghist, sp, st_b1, st_r1);
        k_compact<<<blocks, 256, 0, stream>>>(nll, st_b1, cand, ccnt, st_S);
        k_resolve<<<BN, 256, 0, stream>>>(cand, ccnt, st_b1, st_r1, st_S, accum);
        k_out    <<<1, 64, 0, stream>>>(accum, sp, (float*)d_out);
    }
}

// Round 3
// 244.020 us; speedup vs baseline: 2.0269x; 2.0269x over previous
//
#include <hip/hip_runtime.h>

#define BN    64
#define KCLS  3
#define PPIX  147456
#define NB1   4096

// kernel-1 geometry (verified r0)
#define BPR    36
#define F4_BLK 1024

// rowselect geometry
#define RS_THREADS 1024
#define RS_F4      (PPIX / 4 / RS_THREADS)   // 36 float4 per thread
#define CAPS       8192                      // LDS candidate cap (same as verified CAP)

// ---------------- workspace layout (bytes) ----------------
static const size_t OFF_NLL  = 0;                                   // 37,748,736
static const size_t OFF_GH   = (size_t)BN * PPIX * 4;               // ghist: 1 MB (zeroed)
static const size_t OFF_ACC  = OFF_GH + (size_t)BN * NB1 * 4;       // 8 B (zeroed)
static const size_t OFF_DONE = OFF_ACC + 8;                         // 8 B (zeroed)
static const size_t ZERO_END = OFF_DONE + 8;

__device__ __forceinline__ unsigned topk_count(const int* sp_ptr) {
    double sp = (double)sp_ptr[0];
    if (sp > 1.0) sp = 1.0;
    return (unsigned)(sp * 0.15 * (double)PPIX + (1.0 - sp) * (double)PPIX);
}

__device__ __forceinline__ float sel_nll(int t, float a, float b, float c) {
    float lp = (t == 0) ? a : ((t == 1) ? b : ((t == 2) ? c : 0.0f));
    return fmaxf(-lp, 0.0f);   // nll >= 0; kill -0.0
}

// ---------------- kernel 1: NLL select + store + count histogram ------------
// (byte-identical logic to the verified 253us baseline's k_hist1)
__global__ __launch_bounds__(256) void k_hist1(
    const float* __restrict__ in, const int* __restrict__ tgt,
    float* __restrict__ nll, unsigned* __restrict__ cnt1)
{
    __shared__ unsigned lc[NB1];   // 16 KB only -> 8 blocks/CU
    const int tid = threadIdx.x;
    for (int i = tid; i < NB1; i += 256) lc[i] = 0u;
    __syncthreads();

    const int row   = blockIdx.x / BPR;
    const int chunk = blockIdx.x % BPR;
    const float4* p0 = (const float4*)(in + (size_t)row * KCLS * PPIX);
    const float4* p1 = p0 + PPIX / 4;
    const float4* p2 = p1 + PPIX / 4;
    const int4*   t4 = (const int4*)(tgt + (size_t)row * PPIX);
    float4*       n4 = (float4*)(nll + (size_t)row * PPIX);
    const int base = chunk * F4_BLK;

    #pragma unroll
    for (int j = 0; j < 4; ++j) {
        const int idx = base + j * 256 + tid;
        const int4   t = t4[idx];
        const float4 a = p0[idx];
        const float4 b = p1[idx];
        const float4 c = p2[idx];
        float4 v;
        v.x = sel_nll(t.x, a.x, b.x, c.x);
        v.y = sel_nll(t.y, a.y, b.y, c.y);
        v.z = sel_nll(t.z, a.z, b.z, c.z);
        v.w = sel_nll(t.w, a.w, b.w, c.w);
        n4[idx] = v;
        atomicAdd(&lc[__float_as_uint(v.x) >> 19], 1u);
        atomicAdd(&lc[__float_as_uint(v.y) >> 19], 1u);
        atomicAdd(&lc[__float_as_uint(v.z) >> 19], 1u);
        atomicAdd(&lc[__float_as_uint(v.w) >> 19], 1u);
    }
    __syncthreads();

    unsigned* gc = cnt1 + (size_t)row * NB1;
    for (int i = tid; i < NB1; i += 256) {
        const unsigned cc = lc[i];
        if (cc) atomicAdd(&gc[i], cc);
    }
}

// ---------------- kernel 2: per-row scan + compact + resolve + mean ---------
// One block per row (64 x 1024). No cross-block waiting anywhere: all
// inter-block handoff is the k_hist1->k_rowselect dispatch boundary plus
// device-scope atomics (accum/done ticket) at the very end.
__global__ __launch_bounds__(RS_THREADS, 1) void k_rowselect(
    const float* __restrict__ nll, const unsigned* __restrict__ ghist,
    const int* __restrict__ sp, double* __restrict__ accum,
    unsigned* __restrict__ done, float* __restrict__ out)
{
    __shared__ float    stage[CAPS];     // 32 KB — candidates, persists to resolve
    __shared__ double   dd[RS_THREADS];  // 8 KB — dred, then sum-prefix scratch
    __shared__ unsigned cs[RS_THREADS];  // 4 KB — count-prefix scratch
    __shared__ unsigned lc2[1024];       // 4 KB — level-2/3 count hist
    __shared__ float    ls2[1024];       // 4 KB — level-2/3 sum hist
    __shared__ int s_b1, s_r1, s_lcnt, s_b2, s_r2;
    __shared__ double s_S0, s_S2;

    const int row = blockIdx.x;
    const int tid = threadIdx.x;

    // ---- level 1: descending scan of ghist (4 bins/thread) ----
    const unsigned* ghr = ghist + (size_t)row * NB1;
    unsigned cl[4]; unsigned cacc = 0u;
    #pragma unroll
    for (int i = 0; i < 4; ++i) {
        cl[i] = ghr[NB1 - 1 - (tid * 4 + i)];
        cacc += cl[i];
    }
    cs[tid] = cacc;
    __syncthreads();
    for (int off = 1; off < RS_THREADS; off <<= 1) {
        unsigned t2 = (tid >= off) ? cs[tid - off] : 0u;
        __syncthreads();
        cs[tid] += t2;
        __syncthreads();
    }
    const unsigned k = topk_count(sp);
    {
        unsigned cum = tid ? cs[tid - 1] : 0u;
        #pragma unroll
        for (int i = 0; i < 4; ++i) {
            const unsigned cb = cl[i];
            if (cum < k && cum + cb >= k) {      // exactly one (thread,i) hits
                s_b1 = NB1 - 1 - (tid * 4 + i);
                s_r1 = (int)(k - cum);
            }
            cum += cb;
        }
    }
    if (tid == 0) s_lcnt = 0;
    __syncthreads();

    // ---- stream this row's nll: S_above (f64) + stage bin-b1 candidates ----
    const unsigned b1 = (unsigned)s_b1;
    const unsigned lo = b1 << 19;
    const unsigned hi = (b1 + 1u) << 19;   // b1==4095 -> 0x80000000 > all v>=0
    const float4* n4 = (const float4*)(nll + (size_t)row * PPIX);

    double acc = 0.0;
    #pragma unroll
    for (int j = 0; j < RS_F4; ++j) {
        const float4 f = n4[j * RS_THREADS + tid];
        const float vv[4] = {f.x, f.y, f.z, f.w};
        #pragma unroll
        for (int q = 0; q < 4; ++q) {
            const unsigned u = __float_as_uint(vv[q]);
            if (u >= hi) {
                acc += (double)vv[q];
            } else if (u >= lo) {
                const int s = atomicAdd(&s_lcnt, 1);
                if (s < CAPS) stage[s] = vv[q];   // same cap semantics as verified path
            }
        }
    }
    dd[tid] = acc;
    __syncthreads();
    for (int s = RS_THREADS / 2; s > 0; s >>= 1) {
        if (tid < s) dd[tid] += dd[tid + s];
        __syncthreads();
    }
    if (tid == 0) s_S0 = dd[0];
    int n = s_lcnt; if (n > CAPS) n = CAPS;   // valid: covered by the sync above

    // ---- level 2: 1024-bin hist over bits[18:9] of candidates ----
    lc2[tid] = 0u; ls2[tid] = 0.0f;
    __syncthreads();
    for (int i = tid; i < n; i += RS_THREADS) {
        const float v = stage[i];
        const unsigned key = (__float_as_uint(v) >> 9) & 0x3FFu;
        atomicAdd(&lc2[key], 1u);
        atomicAdd(&ls2[key], v);
    }
    __syncthreads();

    // descending scan, 1 bin/thread
    {
        const unsigned c2 = lc2[1023 - tid];
        const float    f2 = ls2[1023 - tid];
        cs[tid] = c2; dd[tid] = (double)f2;
        __syncthreads();
        for (int off = 1; off < RS_THREADS; off <<= 1) {
            unsigned tc = 0u; double td = 0.0;
            if (tid >= off) { tc = cs[tid - off]; td = dd[tid - off]; }
            __syncthreads();
            cs[tid] += tc; dd[tid] += td;
            __syncthreads();
        }
        const unsigned k2 = (unsigned)s_r1;
        const unsigned cum = tid ? cs[tid - 1] : 0u;
        const double   sS  = tid ? dd[tid - 1] : 0.0;
        if (cum < k2 && cum + c2 >= k2) {        // exactly one thread
            s_b2 = 1023 - tid;
            s_r2 = (int)(k2 - cum);
            s_S2 = sS;
        }
    }
    __syncthreads();

    // ---- level 3: 512-bin hist over bits[8:0], filtered to b2 ----
    const unsigned b2 = (unsigned)s_b2;
    if (tid < 512) { lc2[tid] = 0u; ls2[tid] = 0.0f; }
    __syncthreads();
    for (int i = tid; i < n; i += RS_THREADS) {
        const float v = stage[i];
        const unsigned bits = __float_as_uint(v);
        if (((bits >> 9) & 0x3FFu) == b2) {
            atomicAdd(&lc2[bits & 0x1FFu], 1u);
            atomicAdd(&ls2[bits & 0x1FFu], v);
        }
    }
    __syncthreads();
    {
        const unsigned c3 = (tid < 512) ? lc2[511 - tid] : 0u;
        const float    f3 = (tid < 512) ? ls2[511 - tid] : 0.0f;
        cs[tid] = c3; dd[tid] = (double)f3;
        __syncthreads();
        for (int off = 1; off < RS_THREADS; off <<= 1) {
            unsigned tc = 0u; double td = 0.0;
            if (tid >= off) { tc = cs[tid - off]; td = dd[tid - off]; }
            __syncthreads();
            cs[tid] += tc; dd[tid] += td;
            __syncthreads();
        }
        const unsigned k3 = (unsigned)s_r2;
        const unsigned cum = tid ? cs[tid - 1] : 0u;
        const double   S3  = tid ? dd[tid - 1] : 0.0;
        if (cum < k3 && cum + c3 >= k3) {        // exactly one thread finalizes
            const int      bin3 = 511 - tid;
            const unsigned r3   = k3 - cum;
            const float tval = __uint_as_float((b1 << 19) | (b2 << 9) | (unsigned)bin3);
            const double total = s_S0 + s_S2 + S3 + (double)r3 * (double)tval;
            atomicAdd(accum, total);             // device-scope f64 atomic
            __threadfence();
            const unsigned ticket =
                __hip_atomic_fetch_add(done, 1u, __ATOMIC_ACQ_REL, __HIP_MEMORY_SCOPE_AGENT);
            if (ticket == BN - 1) {              // last row writes the mean
                const double a2 =
                    __hip_atomic_load(accum, __ATOMIC_RELAXED, __HIP_MEMORY_SCOPE_AGENT);
                out[0] = (float)(a2 / ((double)BN * (double)topk_count(sp)));
            }
        }
    }
}

// ======================= launch =============================================
extern "C" void kernel_launch(void* const* d_in, const int* in_sizes, int n_in,
                              void* d_out, int out_size, void* d_ws, size_t ws_size,
                              hipStream_t stream)
{
    (void)in_sizes; (void)n_in; (void)out_size; (void)ws_size;
    const float* in  = (const float*)d_in[0];
    const int*   tgt = (const int*)d_in[1];
    const int*   sp  = (const int*)d_in[2];

    char* ws = (char*)d_ws;
    float*    nll   = (float*)(ws + OFF_NLL);
    unsigned* ghist = (unsigned*)(ws + OFF_GH);
    double*   accum = (double*)(ws + OFF_ACC);
    unsigned* done  = (unsigned*)(ws + OFF_DONE);

    // zero: ghist + accum + done (contiguous)
    hipMemsetAsync(ws + OFF_GH, 0, ZERO_END - OFF_GH, stream);

    k_hist1    <<<BN * BPR, 256,        0, stream>>>(in, tgt, nll, ghist);
    k_rowselect<<<BN,       RS_THREADS, 0, stream>>>(nll, ghist, sp, accum, done,
                                                     (float*)d_out);
}

// Round 4
// 241.927 us; speedup vs baseline: 2.0444x; 1.0086x over previous
//
#include <hip/hip_runtime.h>

#define BN    64
#define KCLS  3
#define PPIX  147456
#define NB1   4096

// kernel-1 geometry: 64 rows x 32 chunks = 2048 blocks = exactly 8 blocks/CU
#define BPR    32
#define F4PB   (PPIX / 4 / BPR)     // 1152 float4 groups per block

// rowselect geometry (unchanged from verified r3)
#define RS_THREADS 1024
#define RS_F4      (PPIX / 4 / RS_THREADS)   // 36 float4 per thread
#define CAPS       8192                      // LDS candidate cap

// ---------------- workspace layout (bytes) ----------------
static const size_t OFF_NLL  = 0;                                   // 37,748,736
static const size_t OFF_GH   = (size_t)BN * PPIX * 4;               // ghist: 1 MB (zeroed)
static const size_t OFF_ACC  = OFF_GH + (size_t)BN * NB1 * 4;       // 8 B (zeroed)
static const size_t OFF_DONE = OFF_ACC + 8;                         // 8 B (zeroed)
static const size_t ZERO_END = OFF_DONE + 8;

__device__ __forceinline__ unsigned topk_count(const int* sp_ptr) {
    double sp = (double)sp_ptr[0];
    if (sp > 1.0) sp = 1.0;
    return (unsigned)(sp * 0.15 * (double)PPIX + (1.0 - sp) * (double)PPIX);
}

__device__ __forceinline__ float sel_nll(int t, float a, float b, float c) {
    float lp = (t == 0) ? a : ((t == 1) ? b : ((t == 2) ? c : 0.0f));
    return fmaxf(-lp, 0.0f);   // nll >= 0; kill -0.0
}

// ---------------- kernel 1: NLL select + store + count histogram ------------
// r4 changes vs r3: (1) 2048-block grid (8/CU, no straggler round);
// (2) explicit register double-buffer so the next iteration's 4 loads are in
// flight while the current iteration computes/atomics.
__global__ __launch_bounds__(256) void k_hist1(
    const float* __restrict__ in, const int* __restrict__ tgt,
    float* __restrict__ nll, unsigned* __restrict__ cnt1)
{
    __shared__ unsigned lc[NB1];   // 16 KB -> 8 blocks/CU by LDS
    const int tid = threadIdx.x;
    for (int i = tid; i < NB1; i += 256) lc[i] = 0u;
    __syncthreads();

    const int row   = blockIdx.x / BPR;
    const int chunk = blockIdx.x % BPR;
    const float4* p0 = (const float4*)(in + (size_t)row * KCLS * PPIX);
    const float4* p1 = p0 + PPIX / 4;
    const float4* p2 = p1 + PPIX / 4;
    const int4*   t4 = (const int4*)(tgt + (size_t)row * PPIX);
    float4*       n4 = (float4*)(nll + (size_t)row * PPIX);
    const int base = chunk * F4PB;
    const bool tail = (tid < (F4PB - 4 * 256));   // tid < 128 does a 5th group

    // prefetch j=0
    int idx_c = base + tid;
    int4   t_c = t4[idx_c];
    float4 a_c = p0[idx_c];
    float4 b_c = p1[idx_c];
    float4 c_c = p2[idx_c];

    #pragma unroll
    for (int j = 0; j < 4; ++j) {
        // prefetch next iteration (j+1) before consuming current
        int idx_n = 0;
        int4 t_n; float4 a_n, b_n, c_n;
        const bool have_next = (j < 3) || tail;
        if (have_next) {
            idx_n = base + (j + 1) * 256 + tid;
            t_n = t4[idx_n];
            a_n = p0[idx_n];
            b_n = p1[idx_n];
            c_n = p2[idx_n];
        }

        float4 v;
        v.x = sel_nll(t_c.x, a_c.x, b_c.x, c_c.x);
        v.y = sel_nll(t_c.y, a_c.y, b_c.y, c_c.y);
        v.z = sel_nll(t_c.z, a_c.z, b_c.z, c_c.z);
        v.w = sel_nll(t_c.w, a_c.w, b_c.w, c_c.w);
        n4[idx_c] = v;
        atomicAdd(&lc[__float_as_uint(v.x) >> 19], 1u);
        atomicAdd(&lc[__float_as_uint(v.y) >> 19], 1u);
        atomicAdd(&lc[__float_as_uint(v.z) >> 19], 1u);
        atomicAdd(&lc[__float_as_uint(v.w) >> 19], 1u);

        idx_c = idx_n; t_c = t_n; a_c = a_n; b_c = b_n; c_c = c_n;
    }

    // tail: 5th group for tid < 128 (data already prefetched above)
    if (tail) {
        float4 v;
        v.x = sel_nll(t_c.x, a_c.x, b_c.x, c_c.x);
        v.y = sel_nll(t_c.y, a_c.y, b_c.y, c_c.y);
        v.z = sel_nll(t_c.z, a_c.z, b_c.z, c_c.z);
        v.w = sel_nll(t_c.w, a_c.w, b_c.w, c_c.w);
        n4[idx_c] = v;
        atomicAdd(&lc[__float_as_uint(v.x) >> 19], 1u);
        atomicAdd(&lc[__float_as_uint(v.y) >> 19], 1u);
        atomicAdd(&lc[__float_as_uint(v.z) >> 19], 1u);
        atomicAdd(&lc[__float_as_uint(v.w) >> 19], 1u);
    }
    __syncthreads();

    unsigned* gc = cnt1 + (size_t)row * NB1;
    for (int i = tid; i < NB1; i += 256) {
        const unsigned cc = lc[i];
        if (cc) atomicAdd(&gc[i], cc);
    }
}

// ---------------- kernel 2: per-row scan + compact + resolve + mean ---------
// (unchanged from verified r3)
__global__ __launch_bounds__(RS_THREADS, 1) void k_rowselect(
    const float* __restrict__ nll, const unsigned* __restrict__ ghist,
    const int* __restrict__ sp, double* __restrict__ accum,
    unsigned* __restrict__ done, float* __restrict__ out)
{
    __shared__ float    stage[CAPS];     // 32 KB — candidates, persists to resolve
    __shared__ double   dd[RS_THREADS];  // 8 KB — dred, then sum-prefix scratch
    __shared__ unsigned cs[RS_THREADS];  // 4 KB — count-prefix scratch
    __shared__ unsigned lc2[1024];       // 4 KB — level-2/3 count hist
    __shared__ float    ls2[1024];       // 4 KB — level-2/3 sum hist
    __shared__ int s_b1, s_r1, s_lcnt, s_b2, s_r2;
    __shared__ double s_S0, s_S2;

    const int row = blockIdx.x;
    const int tid = threadIdx.x;

    // ---- level 1: descending scan of ghist (4 bins/thread) ----
    const unsigned* ghr = ghist + (size_t)row * NB1;
    unsigned cl[4]; unsigned cacc = 0u;
    #pragma unroll
    for (int i = 0; i < 4; ++i) {
        cl[i] = ghr[NB1 - 1 - (tid * 4 + i)];
        cacc += cl[i];
    }
    cs[tid] = cacc;
    __syncthreads();
    for (int off = 1; off < RS_THREADS; off <<= 1) {
        unsigned t2 = (tid >= off) ? cs[tid - off] : 0u;
        __syncthreads();
        cs[tid] += t2;
        __syncthreads();
    }
    const unsigned k = topk_count(sp);
    {
        unsigned cum = tid ? cs[tid - 1] : 0u;
        #pragma unroll
        for (int i = 0; i < 4; ++i) {
            const unsigned cb = cl[i];
            if (cum < k && cum + cb >= k) {      // exactly one (thread,i) hits
                s_b1 = NB1 - 1 - (tid * 4 + i);
                s_r1 = (int)(k - cum);
            }
            cum += cb;
        }
    }
    if (tid == 0) s_lcnt = 0;
    __syncthreads();

    // ---- stream this row's nll: S_above (f64) + stage bin-b1 candidates ----
    const unsigned b1 = (unsigned)s_b1;
    const unsigned lo = b1 << 19;
    const unsigned hi = (b1 + 1u) << 19;   // b1==4095 -> 0x80000000 > all v>=0
    const float4* n4 = (const float4*)(nll + (size_t)row * PPIX);

    double acc = 0.0;
    #pragma unroll
    for (int j = 0; j < RS_F4; ++j) {
        const float4 f = n4[j * RS_THREADS + tid];
        const float vv[4] = {f.x, f.y, f.z, f.w};
        #pragma unroll
        for (int q = 0; q < 4; ++q) {
            const unsigned u = __float_as_uint(vv[q]);
            if (u >= hi) {
                acc += (double)vv[q];
            } else if (u >= lo) {
                const int s = atomicAdd(&s_lcnt, 1);
                if (s < CAPS) stage[s] = vv[q];
            }
        }
    }
    dd[tid] = acc;
    __syncthreads();
    for (int s = RS_THREADS / 2; s > 0; s >>= 1) {
        if (tid < s) dd[tid] += dd[tid + s];
        __syncthreads();
    }
    if (tid == 0) s_S0 = dd[0];
    int n = s_lcnt; if (n > CAPS) n = CAPS;   // valid: covered by the sync above

    // ---- level 2: 1024-bin hist over bits[18:9] of candidates ----
    lc2[tid] = 0u; ls2[tid] = 0.0f;
    __syncthreads();
    for (int i = tid; i < n; i += RS_THREADS) {
        const float v = stage[i];
        const unsigned key = (__float_as_uint(v) >> 9) & 0x3FFu;
        atomicAdd(&lc2[key], 1u);
        atomicAdd(&ls2[key], v);
    }
    __syncthreads();

    // descending scan, 1 bin/thread
    {
        const unsigned c2 = lc2[1023 - tid];
        const float    f2 = ls2[1023 - tid];
        cs[tid] = c2; dd[tid] = (double)f2;
        __syncthreads();
        for (int off = 1; off < RS_THREADS; off <<= 1) {
            unsigned tc = 0u; double td = 0.0;
            if (tid >= off) { tc = cs[tid - off]; td = dd[tid - off]; }
            __syncthreads();
            cs[tid] += tc; dd[tid] += td;
            __syncthreads();
        }
        const unsigned k2 = (unsigned)s_r1;
        const unsigned cum = tid ? cs[tid - 1] : 0u;
        const double   sS  = tid ? dd[tid - 1] : 0.0;
        if (cum < k2 && cum + c2 >= k2) {        // exactly one thread
            s_b2 = 1023 - tid;
            s_r2 = (int)(k2 - cum);
            s_S2 = sS;
        }
    }
    __syncthreads();

    // ---- level 3: 512-bin hist over bits[8:0], filtered to b2 ----
    const unsigned b2 = (unsigned)s_b2;
    if (tid < 512) { lc2[tid] = 0u; ls2[tid] = 0.0f; }
    __syncthreads();
    for (int i = tid; i < n; i += RS_THREADS) {
        const float v = stage[i];
        const unsigned bits = __float_as_uint(v);
        if (((bits >> 9) & 0x3FFu) == b2) {
            atomicAdd(&lc2[bits & 0x1FFu], 1u);
            atomicAdd(&ls2[bits & 0x1FFu], v);
        }
    }
    __syncthreads();
    {
        const unsigned c3 = (tid < 512) ? lc2[511 - tid] : 0u;
        const float    f3 = (tid < 512) ? ls2[511 - tid] : 0.0f;
        cs[tid] = c3; dd[tid] = (double)f3;
        __syncthreads();
        for (int off = 1; off < RS_THREADS; off <<= 1) {
            unsigned tc = 0u; double td = 0.0;
            if (tid >= off) { tc = cs[tid - off]; td = dd[tid - off]; }
            __syncthreads();
            cs[tid] += tc; dd[tid] += td;
            __syncthreads();
        }
        const unsigned k3 = (unsigned)s_r2;
        const unsigned cum = tid ? cs[tid - 1] : 0u;
        const double   S3  = tid ? dd[tid - 1] : 0.0;
        if (cum < k3 && cum + c3 >= k3) {        // exactly one thread finalizes
            const int      bin3 = 511 - tid;
            const unsigned r3   = k3 - cum;
            const float tval = __uint_as_float((b1 << 19) | (b2 << 9) | (unsigned)bin3);
            const double total = s_S0 + s_S2 + S3 + (double)r3 * (double)tval;
            atomicAdd(accum, total);             // device-scope f64 atomic
            __threadfence();
            const unsigned ticket =
                __hip_atomic_fetch_add(done, 1u, __ATOMIC_ACQ_REL, __HIP_MEMORY_SCOPE_AGENT);
            if (ticket == BN - 1) {              // last row writes the mean
                const double a2 =
                    __hip_atomic_load(accum, __ATOMIC_RELAXED, __HIP_MEMORY_SCOPE_AGENT);
                out[0] = (float)(a2 / ((double)BN * (double)topk_count(sp)));
            }
        }
    }
}

// ======================= launch =============================================
extern "C" void kernel_launch(void* const* d_in, const int* in_sizes, int n_in,
                              void* d_out, int out_size, void* d_ws, size_t ws_size,
                              hipStream_t stream)
{
    (void)in_sizes; (void)n_in; (void)out_size; (void)ws_size;
    const float* in  = (const float*)d_in[0];
    const int*   tgt = (const int*)d_in[1];
    const int*   sp  = (const int*)d_in[2];

    char* ws = (char*)d_ws;
    float*    nll   = (float*)(ws + OFF_NLL);
    unsigned* ghist = (unsigned*)(ws + OFF_GH);
    double*   accum = (double*)(ws + OFF_ACC);
    unsigned* done  = (unsigned*)(ws + OFF_DONE);

    // zero: ghist + accum + done (contiguous)
    hipMemsetAsync(ws + OFF_GH, 0, ZERO_END - OFF_GH, stream);

    k_hist1    <<<BN * BPR, 256,        0, stream>>>(in, tgt, nll, ghist);
    k_rowselect<<<BN,       RS_THREADS, 0, stream>>>(nll, ghist, sp, accum, done,
                                                     (float*)d_out);
}